// Round 13
// baseline (458.706 us; speedup 1.0000x reference)
//
#include <hip/hip_runtime.h>

constexpr int HID = 128;
constexpr int NB  = 1024;   // destination-range buckets
constexpr int NCH = 64;     // edge chunks (radix blocks)

typedef __attribute__((ext_vector_type(8))) short short8;
typedef __attribute__((ext_vector_type(8))) unsigned short us8;
typedef __attribute__((ext_vector_type(4))) float f32x4;

__device__ __forceinline__ unsigned short f2bf(float f) {
    union { float f; unsigned u; } v; v.f = f;
    unsigned r = v.u + 0x7fffu + ((v.u >> 16) & 1u);   // RNE
    return (unsigned short)(r >> 16);
}
__device__ __forceinline__ float bf2f(unsigned short u) {
    union { unsigned u; float f; } v; v.u = ((unsigned)u) << 16;
    return v.f;
}

// ---------------- bf16 MFMA GEMM body (non-conv uses) ----------------
// C[nrows,128] (bf16) = epilogue( A @ W^T + bias ), all operands bf16.
// POOL: skip C store, emit per-block col sum/max into part.
template<int K, bool RELU, bool POOL>
__device__ __forceinline__
void mgemm_body(int bid, const unsigned short* __restrict__ A1b,
                const unsigned short* __restrict__ Wb,
                const float* __restrict__ bias, unsigned short* __restrict__ C,
                float* __restrict__ part, int nrows)
{
    constexpr int LDT = 40;
    __shared__ unsigned short lds[2 * 128 * LDT];
    unsigned short* As = lds;
    unsigned short* Ws = lds + 128 * LDT;
    const int tid = threadIdx.x;
    const int w = tid >> 6, l = tid & 63;
    const int lr = l & 15, lg = l >> 4;
    const int row0 = bid * 128;

    f32x4 acc[2][8] = {};
    const int sr = tid >> 1;
    const int sc = (tid & 1) * 16;
    int gr = row0 + sr; if (gr >= nrows) gr = nrows - 1;

    for (int k0 = 0; k0 < K; k0 += 32) {
        const unsigned short* bsrc = A1b + (size_t)gr * K + k0 + sc;
        us8 a0 = *(const us8*)(bsrc + 0);
        us8 a1 = *(const us8*)(bsrc + 8);
        *(us8*)&As[sr * LDT + sc + 0] = a0;
        *(us8*)&As[sr * LDT + sc + 8] = a1;

        const unsigned short* s = Wb + (size_t)sr * K + k0 + sc;
        us8 b0 = *(const us8*)(s + 0);
        us8 b1 = *(const us8*)(s + 8);
        *(us8*)&Ws[sr * LDT + sc + 0] = b0;
        *(us8*)&Ws[sr * LDT + sc + 8] = b1;
        __syncthreads();

        short8 afr[2];
#pragma unroll
        for (int rt = 0; rt < 2; rt++)
            afr[rt] = *(const short8*)&As[(w * 32 + rt * 16 + lr) * LDT + lg * 8];
#pragma unroll
        for (int ct = 0; ct < 8; ct++) {
            short8 bfr = *(const short8*)&Ws[(ct * 16 + lr) * LDT + lg * 8];
#pragma unroll
            for (int rt = 0; rt < 2; rt++)
                acc[rt][ct] = __builtin_amdgcn_mfma_f32_16x16x32_bf16(
                    afr[rt], bfr, acc[rt][ct], 0, 0, 0);
        }
        __syncthreads();
    }

    float bia[8];
#pragma unroll
    for (int ct = 0; ct < 8; ct++) bia[ct] = bias[ct * 16 + lr];
    float ps[8], pm[8];
    if (POOL) {
#pragma unroll
        for (int ct = 0; ct < 8; ct++) { ps[ct] = 0.f; pm[ct] = -3.402823466e+38f; }
    }
#pragma unroll
    for (int rt = 0; rt < 2; rt++) {
#pragma unroll
        for (int r_ = 0; r_ < 4; r_++) {
            int row = row0 + w * 32 + rt * 16 + lg * 4 + r_;
            float v[8];
#pragma unroll
            for (int ct = 0; ct < 8; ct++) v[ct] = acc[rt][ct][r_] + bia[ct];
            if (RELU) {
#pragma unroll
                for (int ct = 0; ct < 8; ct++) v[ct] = fmaxf(v[ct], 0.f);
            }
            if (row < nrows) {
                if (POOL) {
#pragma unroll
                    for (int ct = 0; ct < 8; ct++) {
                        ps[ct] += v[ct];
                        pm[ct] = fmaxf(pm[ct], v[ct]);
                    }
                } else {
#pragma unroll
                    for (int ct = 0; ct < 8; ct++)
                        C[(size_t)row * 128 + ct * 16 + lr] = f2bf(v[ct]);
                }
            }
        }
    }
    if (POOL) {
        float* scr = (float*)lds;
        const int g = w * 4 + lg;
#pragma unroll
        for (int ct = 0; ct < 8; ct++) {
            int col = ct * 16 + lr;
            scr[g * 128 + col] = ps[ct];
            scr[2048 + g * 128 + col] = pm[ct];
        }
        __syncthreads();
        if (tid < 128) {
            float s = 0.f, m = -3.402823466e+38f;
#pragma unroll
            for (int gg = 0; gg < 16; gg++) {
                s += scr[gg * 128 + tid];
                m = fmaxf(m, scr[2048 + gg * 128 + tid]);
            }
            part[bid * 256 + tid] = s;
            part[bid * 256 + 128 + tid] = m;
        }
    }
}

template<int K, bool RELU, bool POOL>
__global__ __launch_bounds__(256)
void mgemm(const unsigned short* __restrict__ A1b, const unsigned short* __restrict__ Wb,
           const float* __restrict__ bias, unsigned short* __restrict__ C,
           float* __restrict__ part, int nrows)
{
    mgemm_body<K,RELU,POOL>(blockIdx.x, A1b, Wb, bias, C, part, nrows);
}

// ---------------- conv_fused: per-block gather -> LDS, then GEMM+LN+ReLU ----
// C = relu(LN( [h | gather(h)] @ W^T + bias )), W is [128][256].
__global__ __launch_bounds__(256)
void conv_fused(const unsigned short* __restrict__ h, const unsigned short* __restrict__ Wb,
                const float* __restrict__ bias, const float* __restrict__ lng,
                const float* __restrict__ lnb,
                const int* __restrict__ offg, const int* __restrict__ degg,
                const int* __restrict__ csr,
                unsigned short* __restrict__ C, int nrows)
{
    constexpr int LDT = 40;
    constexpr int LDN = 132;   // nbr tile stride (halfwords): 264B rows, 2-bank step
    __shared__ unsigned short As[128 * LDT];
    __shared__ unsigned short Ws[128 * LDT];
    __shared__ unsigned short NbrT[128 * LDN];
    const int tid = threadIdx.x;
    const int w = tid >> 6, l = tid & 63;
    const int lr = l & 15, lg = l >> 4;
    const int row0 = blockIdx.x * 128;

    // ---- Phase A: gather this block's 128 nbr rows into NbrT ----
    const unsigned* hp = (const unsigned*)h + l;   // row = 64 uints, lane l owns uint l
    for (int n = 0; n < 32; n++) {
        const int q = row0 + w * 32 + n;
        int d = 0, start = 0;
        if (q < nrows) { start = offg[q]; d = degg[q]; }
        float sx = 0.f, sy = 0.f;
        int i = 0;
        for (; i + 16 <= d; i += 16) {
            int s[16];
#pragma unroll
            for (int j = 0; j < 16; j++) s[j] = csr[start + i + j];
            unsigned u[16];
#pragma unroll
            for (int j = 0; j < 16; j++) u[j] = hp[(size_t)s[j] * 64];
#pragma unroll
            for (int j = 0; j < 16; j++) {
                sx += __uint_as_float(u[j] << 16);
                sy += __uint_as_float(u[j] & 0xffff0000u);
            }
        }
        if (i + 8 <= d) {
            int s[8];
#pragma unroll
            for (int j = 0; j < 8; j++) s[j] = csr[start + i + j];
            unsigned u[8];
#pragma unroll
            for (int j = 0; j < 8; j++) u[j] = hp[(size_t)s[j] * 64];
#pragma unroll
            for (int j = 0; j < 8; j++) {
                sx += __uint_as_float(u[j] << 16);
                sy += __uint_as_float(u[j] & 0xffff0000u);
            }
            i += 8;
        }
        for (; i < d; i++) {
            unsigned u = hp[(size_t)csr[start + i] * 64];
            sx += __uint_as_float(u << 16);
            sy += __uint_as_float(u & 0xffff0000u);
        }
        unsigned o = ((unsigned)f2bf(sx)) | (((unsigned)f2bf(sy)) << 16);
        *(unsigned*)&NbrT[(w * 32 + n) * LDN + l * 2] = o;
    }
    __syncthreads();

    // ---- Phase B: GEMM over K=256 ([h | NbrT]) ----
    f32x4 acc[2][8] = {};
    const int sr = tid >> 1;
    const int sc = (tid & 1) * 16;
    int gr = row0 + sr; if (gr >= nrows) gr = nrows - 1;

#pragma unroll
    for (int k0 = 0; k0 < 256; k0 += 32) {
        if (k0 < 128) {
            const unsigned short* bsrc = h + (size_t)gr * 128 + k0 + sc;
            us8 a0 = *(const us8*)(bsrc + 0);
            us8 a1 = *(const us8*)(bsrc + 8);
            *(us8*)&As[sr * LDT + sc + 0] = a0;
            *(us8*)&As[sr * LDT + sc + 8] = a1;
        }
        const unsigned short* s = Wb + (size_t)sr * 256 + k0 + sc;
        us8 b0 = *(const us8*)(s + 0);
        us8 b1 = *(const us8*)(s + 8);
        *(us8*)&Ws[sr * LDT + sc + 0] = b0;
        *(us8*)&Ws[sr * LDT + sc + 8] = b1;
        __syncthreads();

        short8 afr[2];
#pragma unroll
        for (int rt = 0; rt < 2; rt++) {
            if (k0 < 128)
                afr[rt] = *(const short8*)&As[(w * 32 + rt * 16 + lr) * LDT + lg * 8];
            else
                afr[rt] = *(const short8*)&NbrT[(w * 32 + rt * 16 + lr) * LDN + (k0 - 128) + lg * 8];
        }
#pragma unroll
        for (int ct = 0; ct < 8; ct++) {
            short8 bfr = *(const short8*)&Ws[(ct * 16 + lr) * LDT + lg * 8];
#pragma unroll
            for (int rt = 0; rt < 2; rt++)
                acc[rt][ct] = __builtin_amdgcn_mfma_f32_16x16x32_bf16(
                    afr[rt], bfr, acc[rt][ct], 0, 0, 0);
        }
        __syncthreads();
    }

    // ---- epilogue: bias + LayerNorm + ReLU ----
    float bia[8], g8[8], be[8];
#pragma unroll
    for (int ct = 0; ct < 8; ct++) {
        bia[ct] = bias[ct * 16 + lr];
        g8[ct] = lng[ct * 16 + lr];
        be[ct] = lnb[ct * 16 + lr];
    }
#pragma unroll
    for (int rt = 0; rt < 2; rt++) {
#pragma unroll
        for (int r_ = 0; r_ < 4; r_++) {
            int row = row0 + w * 32 + rt * 16 + lg * 4 + r_;
            float v[8];
#pragma unroll
            for (int ct = 0; ct < 8; ct++) v[ct] = acc[rt][ct][r_] + bia[ct];
            float s = 0.f;
#pragma unroll
            for (int ct = 0; ct < 8; ct++) s += v[ct];
#pragma unroll
            for (int m = 8; m >= 1; m >>= 1) s += __shfl_xor(s, m);
            float mean = s * (1.f / 128.f);
            float q = 0.f;
#pragma unroll
            for (int ct = 0; ct < 8; ct++) { v[ct] -= mean; q += v[ct] * v[ct]; }
#pragma unroll
            for (int m = 8; m >= 1; m >>= 1) q += __shfl_xor(q, m);
            float rstd = rsqrtf(q * (1.f / 128.f) + 1e-5f);
#pragma unroll
            for (int ct = 0; ct < 8; ct++)
                v[ct] = fmaxf(v[ct] * rstd * g8[ct] + be[ct], 0.f);
            if (row < nrows) {
#pragma unroll
                for (int ct = 0; ct < 8; ct++)
                    C[(size_t)row * 128 + ct * 16 + lr] = f2bf(v[ct]);
            }
        }
    }
}

// ---------------- prep0: p1hist || fold || weight cvt || x cvt --------------
__device__ __forceinline__ void cvt8_blk(const float* __restrict__ src,
                                         unsigned short* __restrict__ dst,
                                         int relb, int n)
{
    int i = (relb * 256 + threadIdx.x) * 8;
    if (i + 8 <= n) {
        float4 a = *(const float4*)(src + i);
        float4 b = *(const float4*)(src + i + 4);
        us8 o;
        o[0]=f2bf(a.x); o[1]=f2bf(a.y); o[2]=f2bf(a.z); o[3]=f2bf(a.w);
        o[4]=f2bf(b.x); o[5]=f2bf(b.y); o[6]=f2bf(b.z); o[7]=f2bf(b.w);
        *(us8*)(dst + i) = o;
    } else {
        for (int j = i; j < n; j++) dst[j] = f2bf(src[j]);
    }
}

__global__ __launch_bounds__(256)
void prep0(const float* __restrict__ x, unsigned short* __restrict__ xb, int nx,
           const float* __restrict__ fe_w1, unsigned short* __restrict__ w1b,
           const float* __restrict__ fe_w2, unsigned short* __restrict__ w2b,
           const float* __restrict__ conv_w, unsigned short* __restrict__ cwb,
           const float* __restrict__ out_w, const float* __restrict__ v_w,
           const float* __restrict__ out_b, const float* __restrict__ bv,
           unsigned short* __restrict__ Mb, float* __restrict__ bias2,
           const int* __restrict__ ecol, int* __restrict__ ccnt,
           int range, int ch_sz, int E)
{
    const int b = blockIdx.x;
    const int tid = threadIdx.x;
    if (b < NCH) {
        __shared__ int cnt[NB];
        for (int i = tid; i < NB; i += 256) cnt[i] = 0;
        __syncthreads();
        int e0 = b * ch_sz;
        int e1 = e0 + ch_sz; if (e1 > E) e1 = E;
        int e = e0 + tid;
        for (; e + 768 < e1; e += 1024) {
            int c0 = ecol[e], c1 = ecol[e+256], c2 = ecol[e+512], c3 = ecol[e+768];
            atomicAdd(&cnt[c0 / range], 1);
            atomicAdd(&cnt[c1 / range], 1);
            atomicAdd(&cnt[c2 / range], 1);
            atomicAdd(&cnt[c3 / range], 1);
        }
        for (; e < e1; e += 256)
            atomicAdd(&cnt[ecol[e] / range], 1);
        __syncthreads();
        for (int i = tid; i < NB; i += 256) ccnt[(size_t)i * NCH + b] = cnt[i];
        return;
    }
    int b2 = b - NCH;
    if (b2 < 64) {
        const int i = b2 * 2 + (tid >> 7);
        const int j = tid & 127;
        float s = 0.f;
        for (int k = 0; k < 128; k++)
            s = fmaf(out_w[i*128 + k], v_w[k*128 + j], s);
        Mb[i*128 + j] = f2bf(s + ((i == j) ? 1.f : 0.f));
        if (j == 0) {
            float bb = out_b[i];
            for (int k = 0; k < 128; k++)
                bb = fmaf(out_w[i*128 + k], bv[k], bb);
            bias2[i] = bb;
        }
        return;
    }
    b2 -= 64;
    if (b2 < 16) { cvt8_blk(fe_w1, w1b, b2, 128*256); return; }
    b2 -= 16;
    if (b2 < 8)  { cvt8_blk(fe_w2, w2b, b2, 128*128); return; }
    b2 -= 8;
    if (b2 < 48) { cvt8_blk(conv_w, cwb, b2, 3*128*256); return; }
    b2 -= 48;
    cvt8_blk(x, xb, b2, nx);
}

// ---------------- p2scan: bucket totals + per-(bucket,chunk) bases ----------
__global__ __launch_bounds__(256)
void p2scan(const int* __restrict__ ccnt, int* __restrict__ cbase,
            int* __restrict__ btot, int* __restrict__ bbase)
{
    __shared__ int wsum[4];
    const int t = threadIdx.x;
    int tot[4];
#pragma unroll
    for (int j = 0; j < 4; j++) {
        int b = t * 4 + j;
        const int4* p = (const int4*)(ccnt + (size_t)b * NCH);
        int s = 0;
#pragma unroll
        for (int q = 0; q < NCH / 4; q++) {
            int4 v = p[q];
            s += (v.x + v.y) + (v.z + v.w);
        }
        tot[j] = s;
    }
    int tsum = tot[0] + tot[1] + tot[2] + tot[3];
    int inc = tsum;
#pragma unroll
    for (int d2 = 1; d2 < 64; d2 <<= 1) {
        int u = __shfl_up(inc, d2);
        if ((t & 63) >= d2) inc += u;
    }
    if ((t & 63) == 63) wsum[t >> 6] = inc;
    __syncthreads();
    int woff = 0;
#pragma unroll
    for (int w = 0; w < 4; w++) if (w < (t >> 6)) woff += wsum[w];
    int ex = woff + inc - tsum;
#pragma unroll
    for (int j = 0; j < 4; j++) {
        int b = t * 4 + j;
        bbase[b] = ex;
        btot[b]  = tot[j];
        const int4* p = (const int4*)(ccnt + (size_t)b * NCH);
        int4* q4 = (int4*)(cbase + (size_t)b * NCH);
        int run = ex;
#pragma unroll
        for (int q = 0; q < NCH / 4; q++) {
            int4 v = p[q];
            int4 o;
            o.x = run; run += v.x;
            o.y = run; run += v.y;
            o.z = run; run += v.z;
            o.w = run; run += v.w;
            q4[q] = o;
        }
        ex += tot[j];
    }
}

// ---------------- fe1_scat: p3 scatter (blocks first) || FE1 GEMM -----------
__global__ __launch_bounds__(256)
void fe1_scat(const unsigned short* __restrict__ xb, const unsigned short* __restrict__ w1b,
              const float* __restrict__ fe_b1, unsigned short* __restrict__ outh,
              int nrows,
              const int* __restrict__ erow, const int* __restrict__ ecol,
              const int* __restrict__ cbase, unsigned* __restrict__ grouped,
              int range, int ch_sz, int E)
{
    const int b = blockIdx.x;
    const int tid = threadIdx.x;
    if (b < NCH) {
        const int chunk = b;
        __shared__ int cur[NB];
        for (int i = tid; i < NB; i += 256) cur[i] = cbase[(size_t)i * NCH + chunk];
        __syncthreads();
        int e0 = chunk * ch_sz;
        int e1 = e0 + ch_sz; if (e1 > E) e1 = E;
        int e = e0 + tid;
        for (; e + 768 < e1; e += 1024) {
            int c0 = ecol[e],     r0 = erow[e];
            int c1 = ecol[e+256], r1 = erow[e+256];
            int c2 = ecol[e+512], r2 = erow[e+512];
            int c3 = ecol[e+768], r3 = erow[e+768];
            int bk0 = c0 / range, bk1 = c1 / range, bk2 = c2 / range, bk3 = c3 / range;
            int p0 = atomicAdd(&cur[bk0], 1);
            int p1 = atomicAdd(&cur[bk1], 1);
            int p2 = atomicAdd(&cur[bk2], 1);
            int p3 = atomicAdd(&cur[bk3], 1);
            grouped[p0] = ((unsigned)r0 << 6) | (unsigned)(c0 - bk0 * range);
            grouped[p1] = ((unsigned)r1 << 6) | (unsigned)(c1 - bk1 * range);
            grouped[p2] = ((unsigned)r2 << 6) | (unsigned)(c2 - bk2 * range);
            grouped[p3] = ((unsigned)r3 << 6) | (unsigned)(c3 - bk3 * range);
        }
        for (; e < e1; e += 256) {
            int c = ecol[e], r = erow[e];
            int bk = c / range;
            int pos = atomicAdd(&cur[bk], 1);
            grouped[pos] = ((unsigned)r << 6) | (unsigned)(c - bk * range);
        }
        return;
    }
    mgemm_body<256,true,false>(b - NCH, xb, w1b, fe_b1, outh, nullptr, nrows);
}

// ---------------- fe2_csr2: node CSR build (blocks first) || FE2 GEMM -------
__global__ __launch_bounds__(256)
void fe2_csr2(const unsigned short* __restrict__ hin, const unsigned short* __restrict__ w2b,
              const float* __restrict__ fe_b2, unsigned short* __restrict__ outh,
              int nrows, int nbk,
              const int* __restrict__ bbase, const int* __restrict__ btot,
              const unsigned* __restrict__ grouped, int range, int N,
              int* __restrict__ offg, int* __restrict__ degg, int* __restrict__ csr)
{
    const int b = blockIdx.x;
    const int tid = threadIdx.x;
    if (b >= nbk) {
        mgemm_body<128,false,false>(b - nbk, hin, w2b, fe_b2, outh, nullptr, nrows);
        return;
    }
    const int bk = b;
    __shared__ unsigned ent[2048];
    __shared__ int hist[64];
    __shared__ int cur2[64];
    const int base = bbase[bk];
    int cnt = btot[bk]; if (cnt > 2048) cnt = 2048;   // unreachable for this graph
    for (int i = tid; i < cnt; i += 256) ent[i] = grouped[base + i];
    if (tid < 64) hist[tid] = 0;
    __syncthreads();
    for (int i = tid; i < cnt; i += 256) atomicAdd(&hist[ent[i] & 63], 1);
    __syncthreads();
    if (tid == 0) {
        int run = base;
        const int nodebase = bk * range;
        int nn = N - nodebase; if (nn > range) nn = range;
        for (int j = 0; j < nn; j++) {
            int h = hist[j];
            offg[nodebase + j] = run;
            degg[nodebase + j] = h;
            cur2[j] = run;
            run += h;
        }
    }
    __syncthreads();
    for (int i = tid; i < cnt; i += 256) {
        unsigned v = ent[i];
        int p = atomicAdd(&cur2[v & 63], 1);
        csr[p] = (int)(v >> 6);
    }
}

// ---------------- pooling tail ----------------
__global__ __launch_bounds__(256)
void pool_reduce16(const float* __restrict__ part, float* __restrict__ part2,
                   int nblocks)
{
    const int t = threadIdx.x;
    const int b0 = blockIdx.x;
    if (t < 128) {
        float s = 0.f;
        for (int b = b0; b < nblocks; b += 16) s += part[b*256 + t];
        part2[b0*256 + t] = s;
    } else {
        float m = -3.402823466e+38f;
        for (int b = b0; b < nblocks; b += 16) m = fmaxf(m, part[b*256 + t]);
        part2[b0*256 + t] = m;
    }
}

__global__ __launch_bounds__(256)
void cls_fused(const float* __restrict__ part2, int n,
               const float* __restrict__ cw1, const float* __restrict__ cb1,
               const float* __restrict__ cw2, const float* __restrict__ cb2,
               float* __restrict__ out, int classes)
{
    __shared__ float g[256];
    __shared__ float t1[128];
    const int tid = threadIdx.x;
    if (tid < 128) {
        float s = 0.f;
#pragma unroll
        for (int b = 0; b < 16; b++) s += part2[b*256 + tid];
        g[tid] = s / (float)n;
    } else {
        float m = -3.402823466e+38f;
#pragma unroll
        for (int b = 0; b < 16; b++) m = fmaxf(m, part2[b*256 + tid]);
        g[tid] = m;
    }
    __syncthreads();
    const int w = tid >> 6, lane = tid & 63;
    float4 gv = *(const float4*)&g[lane*4];
#pragma unroll 4
    for (int i = 0; i < 32; i++) {
        int r = w * 32 + i;
        float4 wv = *(const float4*)(cw1 + (size_t)r*256 + lane*4);
        float p = wv.x*gv.x + wv.y*gv.y + wv.z*gv.z + wv.w*gv.w;
#pragma unroll
        for (int m = 32; m >= 1; m >>= 1) p += __shfl_xor(p, m);
        if (lane == 0) t1[r] = fmaxf(p + cb1[r], 0.f);
    }
    __syncthreads();
    if (tid < 128) {
        int c = tid >> 6;
        if (c < classes) {
            float p = t1[lane] * cw2[c*128 + lane] + t1[lane+64] * cw2[c*128 + lane + 64];
#pragma unroll
            for (int m = 32; m >= 1; m >>= 1) p += __shfl_xor(p, m);
            if (lane == 0) out[c] = p + cb2[c];
        }
    }
}

extern "C" void kernel_launch(void* const* d_in, const int* in_sizes, int n_in,
                              void* d_out, int out_size, void* d_ws, size_t ws_size,
                              hipStream_t stream)
{
    const float* x        = (const float*)d_in[0];
    const int*   ei       = (const int*)  d_in[1];
    const float* fe_w1    = (const float*)d_in[3];
    const float* fe_b1    = (const float*)d_in[4];
    const float* fe_w2    = (const float*)d_in[5];
    const float* fe_b2    = (const float*)d_in[6];
    const float* conv_w   = (const float*)d_in[7];
    const float* conv_b   = (const float*)d_in[8];
    const float* ln_g     = (const float*)d_in[9];
    const float* ln_b     = (const float*)d_in[10];
    const float* in_proj_w= (const float*)d_in[11];
    const float* in_proj_b= (const float*)d_in[12];
    const float* out_w    = (const float*)d_in[13];
    const float* out_b    = (const float*)d_in[14];
    const float* c_w1     = (const float*)d_in[15];
    const float* c_b1     = (const float*)d_in[16];
    const float* c_w2     = (const float*)d_in[17];
    const float* c_b2     = (const float*)d_in[18];
    float* out = (float*)d_out;

    const int N = in_sizes[0] / 256;
    const int E = in_sizes[1] / 2;
    const int NX = in_sizes[0];
    const int CLASSES = out_size;
    const int* erow = ei;
    const int* ecol = ei + E;

    const int range = (N + NB - 1) / NB;        // nodes per bucket
    const int nbk   = (N + range - 1) / range;  // buckets used
    const int ch_sz = (E + NCH - 1) / NCH;      // edges per radix chunk

    const size_t NH = (size_t)N * HID;

    unsigned short* hb0   = (unsigned short*)d_ws;          // NH bf16
    unsigned short* hb1   = hb0 + NH;                       // NH bf16
    unsigned short* xb    = hb1 + NH;                       // NX bf16
    float*          part  = (float*)(xb + NX);              // 512*256
    float*          part2 = part + 512*256;                 // 16*256
    float*          bias2 = part2 + 16*256;                 // 128
    unsigned short* w1b   = (unsigned short*)(bias2 + 128); // 128*256
    unsigned short* w2b   = w1b + 128*256;                  // 128*128
    unsigned short* cwb   = w2b + 128*128;                  // 3*128*256
    unsigned short* Mb    = cwb + 3*128*256;                // 128*128
    int*            ccnt  = (int*)(Mb + 128*128);           // NB*NCH
    int*            cbase = ccnt + NB*NCH;                  // NB*NCH
    int*            btot  = cbase + NB*NCH;                 // NB
    int*            bbase = btot + NB;                      // NB
    int*            offg  = bbase + NB;                     // N
    int*            degg  = offg + N;                       // N
    int*            csr   = degg + N;                       // E
    unsigned*       grouped = (unsigned*)(csr + E);         // E

    const int gblocks = (N + 127) / 128;
    const int nxb = (NX + 2047) / 2048;
    dim3 blk(256);

    // ---- prep0: p1hist || attn fold || weight cvt || x cvt ----
    prep0<<<NCH + 64 + 16 + 8 + 48 + nxb, blk, 0, stream>>>(
        x, xb, NX, fe_w1, w1b, fe_w2, w2b, conv_w, cwb,
        out_w, in_proj_w + (size_t)2*HID*HID, out_b, in_proj_b + 2*HID,
        Mb, bias2, ecol, ccnt, range, ch_sz, E);

    // ---- p2scan (coalesced, [NB][NCH] layout) ----
    p2scan<<<1, blk, 0, stream>>>(ccnt, cbase, btot, bbase);

    // ---- p3 scatter (first) || FE1 GEMM ----
    fe1_scat<<<NCH + gblocks, blk, 0, stream>>>(
        xb, w1b, fe_b1, hb1, N, erow, ecol, cbase, grouped, range, ch_sz, E);

    // ---- per-bucket node CSR (first) || FE2 GEMM ----
    fe2_csr2<<<nbk + gblocks, blk, 0, stream>>>(
        hb1, w2b, fe_b2, hb0, N, nbk, bbase, btot, grouped, range, N,
        offg, degg, csr);

    // ---- 3 x DynamicGraphConv (gather fused into GEMM) ----
    unsigned short* h = hb0;
    unsigned short* other = hb1;
    for (int l = 0; l < 3; l++) {
        conv_fused<<<gblocks, blk, 0, stream>>>(
            h, cwb + (size_t)l*128*256, conv_b + l*HID,
            ln_g + l*HID, ln_b + l*HID, offg, degg, csr, other, N);
        unsigned short* t = h; h = other; other = t;
    }

    // ---- attention (folded) + pooling in epilogue ----
    mgemm<128,false,true><<<gblocks, blk, 0, stream>>>(
        h, Mb, bias2, nullptr, part, N);

    // ---- pooling tail + classifier ----
    pool_reduce16<<<16, blk, 0, stream>>>(part, part2, gblocks);
    cls_fused<<<1, blk, 0, stream>>>(part2, N, c_w1, c_b1, c_w2, c_b2, out, CLASSES);
}

// Round 14
// 271.940 us; speedup vs baseline: 1.6868x; 1.6868x over previous
//
#include <hip/hip_runtime.h>

constexpr int HID = 128;
constexpr int NB  = 1024;   // destination-range buckets
constexpr int NCH = 64;     // edge chunks (radix blocks)

typedef __attribute__((ext_vector_type(8))) short short8;
typedef __attribute__((ext_vector_type(8))) unsigned short us8;
typedef __attribute__((ext_vector_type(4))) float f32x4;

__device__ __forceinline__ unsigned short f2bf(float f) {
    union { float f; unsigned u; } v; v.f = f;
    unsigned r = v.u + 0x7fffu + ((v.u >> 16) & 1u);   // RNE
    return (unsigned short)(r >> 16);
}
__device__ __forceinline__ float bf2f(unsigned short u) {
    union { unsigned u; float f; } v; v.u = ((unsigned)u) << 16;
    return v.f;
}

// ---------------- bf16 MFMA GEMM body ----------------
// C[nrows,128] (bf16) = epilogue( A @ W^T + bias ), all operands bf16.
// CONCAT: A = [A1b | A2b]. POOL: skip C store, emit per-block col sum/max.
template<int K, bool CONCAT, bool RELU, bool LN, bool POOL>
__device__ __forceinline__
void mgemm_body(int bid, const unsigned short* __restrict__ A1b,
                const unsigned short* __restrict__ A2b,
                const unsigned short* __restrict__ Wb,
                const float* __restrict__ bias, const float* __restrict__ lng,
                const float* __restrict__ lnb, unsigned short* __restrict__ C,
                float* __restrict__ part, int nrows)
{
    constexpr int LDT = 40;
    __shared__ unsigned short lds[2 * 128 * LDT];
    unsigned short* As = lds;
    unsigned short* Ws = lds + 128 * LDT;
    const int tid = threadIdx.x;
    const int w = tid >> 6, l = tid & 63;
    const int lr = l & 15, lg = l >> 4;
    const int row0 = bid * 128;

    f32x4 acc[2][8] = {};
    const int sr = tid >> 1;
    const int sc = (tid & 1) * 16;
    int gr = row0 + sr; if (gr >= nrows) gr = nrows - 1;

    for (int k0 = 0; k0 < K; k0 += 32) {
        const unsigned short* bsrc;
        if (CONCAT) bsrc = ((k0 < 128) ? A1b : A2b) + (size_t)gr * 128 + (k0 & 127) + sc;
        else        bsrc = A1b + (size_t)gr * K + k0 + sc;
        us8 a0 = *(const us8*)(bsrc + 0);
        us8 a1 = *(const us8*)(bsrc + 8);
        *(us8*)&As[sr * LDT + sc + 0] = a0;
        *(us8*)&As[sr * LDT + sc + 8] = a1;

        const unsigned short* s = Wb + (size_t)sr * K + k0 + sc;
        us8 b0 = *(const us8*)(s + 0);
        us8 b1 = *(const us8*)(s + 8);
        *(us8*)&Ws[sr * LDT + sc + 0] = b0;
        *(us8*)&Ws[sr * LDT + sc + 8] = b1;
        __syncthreads();

        short8 afr[2];
#pragma unroll
        for (int rt = 0; rt < 2; rt++)
            afr[rt] = *(const short8*)&As[(w * 32 + rt * 16 + lr) * LDT + lg * 8];
#pragma unroll
        for (int ct = 0; ct < 8; ct++) {
            short8 bfr = *(const short8*)&Ws[(ct * 16 + lr) * LDT + lg * 8];
#pragma unroll
            for (int rt = 0; rt < 2; rt++)
                acc[rt][ct] = __builtin_amdgcn_mfma_f32_16x16x32_bf16(
                    afr[rt], bfr, acc[rt][ct], 0, 0, 0);
        }
        __syncthreads();
    }

    float bia[8], g8[8], be[8];
#pragma unroll
    for (int ct = 0; ct < 8; ct++) {
        bia[ct] = bias[ct * 16 + lr];
        if (LN) { g8[ct] = lng[ct * 16 + lr]; be[ct] = lnb[ct * 16 + lr]; }
    }
    float ps[8], pm[8];
    if (POOL) {
#pragma unroll
        for (int ct = 0; ct < 8; ct++) { ps[ct] = 0.f; pm[ct] = -3.402823466e+38f; }
    }
#pragma unroll
    for (int rt = 0; rt < 2; rt++) {
#pragma unroll
        for (int r_ = 0; r_ < 4; r_++) {
            int row = row0 + w * 32 + rt * 16 + lg * 4 + r_;
            float v[8];
#pragma unroll
            for (int ct = 0; ct < 8; ct++) v[ct] = acc[rt][ct][r_] + bia[ct];
            if (LN) {
                float s = 0.f;
#pragma unroll
                for (int ct = 0; ct < 8; ct++) s += v[ct];
#pragma unroll
                for (int m = 8; m >= 1; m >>= 1) s += __shfl_xor(s, m);
                float mean = s * (1.f / 128.f);
                float q = 0.f;
#pragma unroll
                for (int ct = 0; ct < 8; ct++) { v[ct] -= mean; q += v[ct] * v[ct]; }
#pragma unroll
                for (int m = 8; m >= 1; m >>= 1) q += __shfl_xor(q, m);
                float rstd = rsqrtf(q * (1.f / 128.f) + 1e-5f);
#pragma unroll
                for (int ct = 0; ct < 8; ct++) v[ct] = v[ct] * rstd * g8[ct] + be[ct];
            }
            if (RELU) {
#pragma unroll
                for (int ct = 0; ct < 8; ct++) v[ct] = fmaxf(v[ct], 0.f);
            }
            if (row < nrows) {
                if (POOL) {
#pragma unroll
                    for (int ct = 0; ct < 8; ct++) {
                        ps[ct] += v[ct];
                        pm[ct] = fmaxf(pm[ct], v[ct]);
                    }
                } else {
#pragma unroll
                    for (int ct = 0; ct < 8; ct++)
                        C[(size_t)row * 128 + ct * 16 + lr] = f2bf(v[ct]);
                }
            }
        }
    }
    if (POOL) {
        float* scr = (float*)lds;
        const int g = w * 4 + lg;
#pragma unroll
        for (int ct = 0; ct < 8; ct++) {
            int col = ct * 16 + lr;
            scr[g * 128 + col] = ps[ct];
            scr[2048 + g * 128 + col] = pm[ct];
        }
        __syncthreads();
        if (tid < 128) {
            float s = 0.f, m = -3.402823466e+38f;
#pragma unroll
            for (int gg = 0; gg < 16; gg++) {
                s += scr[gg * 128 + tid];
                m = fmaxf(m, scr[2048 + gg * 128 + tid]);
            }
            part[bid * 256 + tid] = s;
            part[bid * 256 + 128 + tid] = m;
        }
    }
}

template<int K, bool CONCAT, bool RELU, bool LN, bool POOL>
__global__ __launch_bounds__(256)
void mgemm(const unsigned short* __restrict__ A1b, const unsigned short* __restrict__ A2b,
           const unsigned short* __restrict__ Wb, const float* __restrict__ bias,
           const float* __restrict__ lng, const float* __restrict__ lnb,
           unsigned short* __restrict__ C, float* __restrict__ part, int nrows)
{
    mgemm_body<K,CONCAT,RELU,LN,POOL>(blockIdx.x, A1b, A2b, Wb, bias, lng, lnb,
                                      C, part, nrows);
}

// ---------------- prep0: p1hist || fold || weight cvt || x cvt --------------
__device__ __forceinline__ void cvt8_blk(const float* __restrict__ src,
                                         unsigned short* __restrict__ dst,
                                         int relb, int n)
{
    int i = (relb * 256 + threadIdx.x) * 8;
    if (i + 8 <= n) {
        float4 a = *(const float4*)(src + i);
        float4 b = *(const float4*)(src + i + 4);
        us8 o;
        o[0]=f2bf(a.x); o[1]=f2bf(a.y); o[2]=f2bf(a.z); o[3]=f2bf(a.w);
        o[4]=f2bf(b.x); o[5]=f2bf(b.y); o[6]=f2bf(b.z); o[7]=f2bf(b.w);
        *(us8*)(dst + i) = o;
    } else {
        for (int j = i; j < n; j++) dst[j] = f2bf(src[j]);
    }
}

__global__ __launch_bounds__(256)
void prep0(const float* __restrict__ x, unsigned short* __restrict__ xb, int nx,
           const float* __restrict__ fe_w1, unsigned short* __restrict__ w1b,
           const float* __restrict__ fe_w2, unsigned short* __restrict__ w2b,
           const float* __restrict__ conv_w, unsigned short* __restrict__ cwb,
           const float* __restrict__ out_w, const float* __restrict__ v_w,
           const float* __restrict__ out_b, const float* __restrict__ bv,
           unsigned short* __restrict__ Mb, float* __restrict__ bias2,
           const int* __restrict__ ecol, int* __restrict__ ccnt,
           int range, int ch_sz, int E)
{
    const int b = blockIdx.x;
    const int tid = threadIdx.x;
    if (b < NCH) {
        __shared__ int cnt[NB];
        for (int i = tid; i < NB; i += 256) cnt[i] = 0;
        __syncthreads();
        int e0 = b * ch_sz;
        int e1 = e0 + ch_sz; if (e1 > E) e1 = E;
        int e = e0 + tid;
        for (; e + 768 < e1; e += 1024) {
            int c0 = ecol[e], c1 = ecol[e+256], c2 = ecol[e+512], c3 = ecol[e+768];
            atomicAdd(&cnt[c0 / range], 1);
            atomicAdd(&cnt[c1 / range], 1);
            atomicAdd(&cnt[c2 / range], 1);
            atomicAdd(&cnt[c3 / range], 1);
        }
        for (; e < e1; e += 256)
            atomicAdd(&cnt[ecol[e] / range], 1);
        __syncthreads();
        for (int i = tid; i < NB; i += 256) ccnt[(size_t)i * NCH + b] = cnt[i];
        return;
    }
    int b2 = b - NCH;
    if (b2 < 64) {
        const int i = b2 * 2 + (tid >> 7);
        const int j = tid & 127;
        float s = 0.f;
        for (int k = 0; k < 128; k++)
            s = fmaf(out_w[i*128 + k], v_w[k*128 + j], s);
        Mb[i*128 + j] = f2bf(s + ((i == j) ? 1.f : 0.f));
        if (j == 0) {
            float bb = out_b[i];
            for (int k = 0; k < 128; k++)
                bb = fmaf(out_w[i*128 + k], bv[k], bb);
            bias2[i] = bb;
        }
        return;
    }
    b2 -= 64;
    if (b2 < 16) { cvt8_blk(fe_w1, w1b, b2, 128*256); return; }
    b2 -= 16;
    if (b2 < 8)  { cvt8_blk(fe_w2, w2b, b2, 128*128); return; }
    b2 -= 8;
    if (b2 < 48) { cvt8_blk(conv_w, cwb, b2, 3*128*256); return; }
    b2 -= 48;
    cvt8_blk(x, xb, b2, nx);
}

// ---------------- p2scan: bucket totals + per-(bucket,chunk) bases ----------
// ccnt/cbase layout [NB][NCH]: per-bucket data contiguous -> coalesced int4.
__global__ __launch_bounds__(256)
void p2scan(const int* __restrict__ ccnt, int* __restrict__ cbase,
            int* __restrict__ btot, int* __restrict__ bbase)
{
    __shared__ int wsum[4];
    const int t = threadIdx.x;
    int tot[4];
#pragma unroll
    for (int j = 0; j < 4; j++) {
        int b = t * 4 + j;
        const int4* p = (const int4*)(ccnt + (size_t)b * NCH);
        int s = 0;
#pragma unroll
        for (int q = 0; q < NCH / 4; q++) {
            int4 v = p[q];
            s += (v.x + v.y) + (v.z + v.w);
        }
        tot[j] = s;
    }
    int tsum = tot[0] + tot[1] + tot[2] + tot[3];
    int inc = tsum;
#pragma unroll
    for (int d2 = 1; d2 < 64; d2 <<= 1) {
        int u = __shfl_up(inc, d2);
        if ((t & 63) >= d2) inc += u;
    }
    if ((t & 63) == 63) wsum[t >> 6] = inc;
    __syncthreads();
    int woff = 0;
#pragma unroll
    for (int w = 0; w < 4; w++) if (w < (t >> 6)) woff += wsum[w];
    int ex = woff + inc - tsum;
#pragma unroll
    for (int j = 0; j < 4; j++) {
        int b = t * 4 + j;
        bbase[b] = ex;
        btot[b]  = tot[j];
        const int4* p = (const int4*)(ccnt + (size_t)b * NCH);
        int4* q4 = (int4*)(cbase + (size_t)b * NCH);
        int run = ex;
#pragma unroll
        for (int q = 0; q < NCH / 4; q++) {
            int4 v = p[q];
            int4 o;
            o.x = run; run += v.x;
            o.y = run; run += v.y;
            o.z = run; run += v.z;
            o.w = run; run += v.w;
            q4[q] = o;
        }
        ex += tot[j];
    }
}

// ---------------- fe1_scat: p3 scatter (blocks first) || FE1 GEMM -----------
__global__ __launch_bounds__(256)
void fe1_scat(const unsigned short* __restrict__ xb, const unsigned short* __restrict__ w1b,
              const float* __restrict__ fe_b1, unsigned short* __restrict__ outh,
              int nrows,
              const int* __restrict__ erow, const int* __restrict__ ecol,
              const int* __restrict__ cbase, unsigned* __restrict__ grouped,
              int range, int ch_sz, int E)
{
    const int b = blockIdx.x;
    const int tid = threadIdx.x;
    if (b < NCH) {
        const int chunk = b;
        __shared__ int cur[NB];
        for (int i = tid; i < NB; i += 256) cur[i] = cbase[(size_t)i * NCH + chunk];
        __syncthreads();
        int e0 = chunk * ch_sz;
        int e1 = e0 + ch_sz; if (e1 > E) e1 = E;
        int e = e0 + tid;
        for (; e + 768 < e1; e += 1024) {
            int c0 = ecol[e],     r0 = erow[e];
            int c1 = ecol[e+256], r1 = erow[e+256];
            int c2 = ecol[e+512], r2 = erow[e+512];
            int c3 = ecol[e+768], r3 = erow[e+768];
            int bk0 = c0 / range, bk1 = c1 / range, bk2 = c2 / range, bk3 = c3 / range;
            int p0 = atomicAdd(&cur[bk0], 1);
            int p1 = atomicAdd(&cur[bk1], 1);
            int p2 = atomicAdd(&cur[bk2], 1);
            int p3 = atomicAdd(&cur[bk3], 1);
            grouped[p0] = ((unsigned)r0 << 6) | (unsigned)(c0 - bk0 * range);
            grouped[p1] = ((unsigned)r1 << 6) | (unsigned)(c1 - bk1 * range);
            grouped[p2] = ((unsigned)r2 << 6) | (unsigned)(c2 - bk2 * range);
            grouped[p3] = ((unsigned)r3 << 6) | (unsigned)(c3 - bk3 * range);
        }
        for (; e < e1; e += 256) {
            int c = ecol[e], r = erow[e];
            int bk = c / range;
            int pos = atomicAdd(&cur[bk], 1);
            grouped[pos] = ((unsigned)r << 6) | (unsigned)(c - bk * range);
        }
        return;
    }
    mgemm_body<256,false,true,false,false>(
        b - NCH, xb, nullptr, w1b, fe_b1, nullptr, nullptr, outh, nullptr, nrows);
}

// ---------------- fe2_csr2: node CSR build (blocks first) || FE2 GEMM -------
__global__ __launch_bounds__(256)
void fe2_csr2(const unsigned short* __restrict__ hin, const unsigned short* __restrict__ w2b,
              const float* __restrict__ fe_b2, unsigned short* __restrict__ outh,
              int nrows, int nbk,
              const int* __restrict__ bbase, const int* __restrict__ btot,
              const unsigned* __restrict__ grouped, int range, int N,
              int* __restrict__ offg, int* __restrict__ degg, int* __restrict__ csr)
{
    const int b = blockIdx.x;
    const int tid = threadIdx.x;
    if (b >= nbk) {
        mgemm_body<128,false,false,false,false>(
            b - nbk, hin, nullptr, w2b, fe_b2, nullptr, nullptr, outh, nullptr, nrows);
        return;
    }
    const int bk = b;
    __shared__ unsigned ent[2048];
    __shared__ int hist[64];
    __shared__ int cur2[64];
    const int base = bbase[bk];
    int cnt = btot[bk]; if (cnt > 2048) cnt = 2048;   // unreachable for this graph
    for (int i = tid; i < cnt; i += 256) ent[i] = grouped[base + i];
    if (tid < 64) hist[tid] = 0;
    __syncthreads();
    for (int i = tid; i < cnt; i += 256) atomicAdd(&hist[ent[i] & 63], 1);
    __syncthreads();
    if (tid == 0) {
        int run = base;
        const int nodebase = bk * range;
        int nn = N - nodebase; if (nn > range) nn = range;
        for (int j = 0; j < nn; j++) {
            int h = hist[j];
            offg[nodebase + j] = run;
            degg[nodebase + j] = h;
            cur2[j] = run;
            run += h;
        }
    }
    __syncthreads();
    for (int i = tid; i < cnt; i += 256) {
        unsigned v = ent[i];
        int p = atomicAdd(&cur2[v & 63], 1);
        csr[p] = (int)(v >> 6);
    }
}

// nbr[c] (bf16) = sum over in-edges of h[src] (bf16), fp32 accum.
__global__ __launch_bounds__(256)
void gather_sum(const unsigned short* __restrict__ h, const int* __restrict__ offg,
                const int* __restrict__ degg, const int* __restrict__ csr,
                unsigned short* __restrict__ nbr, int N)
{
    int gw = (blockIdx.x * 256 + threadIdx.x) >> 6;
    if (gw >= N) return;
    const int lane = threadIdx.x & 63;
    const int start = offg[gw];
    const int d = degg[gw];
    const unsigned* hp = (const unsigned*)h + lane;
    float ax[8] = {}, ay[8] = {};
    int i = 0;
    for (; i + 8 <= d; i += 8) {
        int s[8];
#pragma unroll
        for (int j = 0; j < 8; j++) s[j] = csr[start + i + j];
        unsigned u[8];
#pragma unroll
        for (int j = 0; j < 8; j++) u[j] = hp[(size_t)s[j] * 64];
#pragma unroll
        for (int j = 0; j < 8; j++) {
            ax[j] += __uint_as_float(u[j] << 16);
            ay[j] += __uint_as_float(u[j] & 0xffff0000u);
        }
    }
    for (; i < d; i++) {
        unsigned u = hp[(size_t)csr[start + i] * 64];
        ax[0] += __uint_as_float(u << 16);
        ay[0] += __uint_as_float(u & 0xffff0000u);
    }
    float sx = ((ax[0]+ax[1]) + (ax[2]+ax[3])) + ((ax[4]+ax[5]) + (ax[6]+ax[7]));
    float sy = ((ay[0]+ay[1]) + (ay[2]+ay[3])) + ((ay[4]+ay[5]) + (ay[6]+ay[7]));
    unsigned o = ((unsigned)f2bf(sx)) | (((unsigned)f2bf(sy)) << 16);
    *((unsigned*)nbr + (size_t)gw * 64 + lane) = o;
}

// ---------------- pooling tail ----------------
__global__ __launch_bounds__(256)
void pool_reduce16(const float* __restrict__ part, float* __restrict__ part2,
                   int nblocks)
{
    const int t = threadIdx.x;
    const int b0 = blockIdx.x;
    if (t < 128) {
        float s = 0.f;
        for (int b = b0; b < nblocks; b += 16) s += part[b*256 + t];
        part2[b0*256 + t] = s;
    } else {
        float m = -3.402823466e+38f;
        for (int b = b0; b < nblocks; b += 16) m = fmaxf(m, part[b*256 + t]);
        part2[b0*256 + t] = m;
    }
}

__global__ __launch_bounds__(256)
void cls_fused(const float* __restrict__ part2, int n,
               const float* __restrict__ cw1, const float* __restrict__ cb1,
               const float* __restrict__ cw2, const float* __restrict__ cb2,
               float* __restrict__ out, int classes)
{
    __shared__ float g[256];
    __shared__ float t1[128];
    const int tid = threadIdx.x;
    if (tid < 128) {
        float s = 0.f;
#pragma unroll
        for (int b = 0; b < 16; b++) s += part2[b*256 + tid];
        g[tid] = s / (float)n;
    } else {
        float m = -3.402823466e+38f;
#pragma unroll
        for (int b = 0; b < 16; b++) m = fmaxf(m, part2[b*256 + tid]);
        g[tid] = m;
    }
    __syncthreads();
    const int w = tid >> 6, lane = tid & 63;
    float4 gv = *(const float4*)&g[lane*4];
#pragma unroll 4
    for (int i = 0; i < 32; i++) {
        int r = w * 32 + i;
        float4 wv = *(const float4*)(cw1 + (size_t)r*256 + lane*4);
        float p = wv.x*gv.x + wv.y*gv.y + wv.z*gv.z + wv.w*gv.w;
#pragma unroll
        for (int m = 32; m >= 1; m >>= 1) p += __shfl_xor(p, m);
        if (lane == 0) t1[r] = fmaxf(p + cb1[r], 0.f);
    }
    __syncthreads();
    if (tid < 128) {
        int c = tid >> 6;
        if (c < classes) {
            float p = t1[lane] * cw2[c*128 + lane] + t1[lane+64] * cw2[c*128 + lane + 64];
#pragma unroll
            for (int m = 32; m >= 1; m >>= 1) p += __shfl_xor(p, m);
            if (lane == 0) out[c] = p + cb2[c];
        }
    }
}

extern "C" void kernel_launch(void* const* d_in, const int* in_sizes, int n_in,
                              void* d_out, int out_size, void* d_ws, size_t ws_size,
                              hipStream_t stream)
{
    const float* x        = (const float*)d_in[0];
    const int*   ei       = (const int*)  d_in[1];
    const float* fe_w1    = (const float*)d_in[3];
    const float* fe_b1    = (const float*)d_in[4];
    const float* fe_w2    = (const float*)d_in[5];
    const float* fe_b2    = (const float*)d_in[6];
    const float* conv_w   = (const float*)d_in[7];
    const float* conv_b   = (const float*)d_in[8];
    const float* ln_g     = (const float*)d_in[9];
    const float* ln_b     = (const float*)d_in[10];
    const float* in_proj_w= (const float*)d_in[11];
    const float* in_proj_b= (const float*)d_in[12];
    const float* out_w    = (const float*)d_in[13];
    const float* out_b    = (const float*)d_in[14];
    const float* c_w1     = (const float*)d_in[15];
    const float* c_b1     = (const float*)d_in[16];
    const float* c_w2     = (const float*)d_in[17];
    const float* c_b2     = (const float*)d_in[18];
    float* out = (float*)d_out;

    const int N = in_sizes[0] / 256;
    const int E = in_sizes[1] / 2;
    const int NX = in_sizes[0];
    const int CLASSES = out_size;
    const int* erow = ei;
    const int* ecol = ei + E;

    const int range = (N + NB - 1) / NB;        // nodes per bucket
    const int nbk   = (N + range - 1) / range;  // buckets used
    const int ch_sz = (E + NCH - 1) / NCH;      // edges per radix chunk

    const size_t NH = (size_t)N * HID;

    unsigned short* nbrb  = (unsigned short*)d_ws;          // NH bf16
    unsigned short* hb0   = nbrb + NH;                      // NH bf16
    unsigned short* hb1   = hb0 + NH;                       // NH bf16
    unsigned short* xb    = hb1 + NH;                       // NX bf16
    float*          part  = (float*)(xb + NX);              // 512*256
    float*          part2 = part + 512*256;                 // 16*256
    float*          bias2 = part2 + 16*256;                 // 128
    unsigned short* w1b   = (unsigned short*)(bias2 + 128); // 128*256
    unsigned short* w2b   = w1b + 128*256;                  // 128*128
    unsigned short* cwb   = w2b + 128*128;                  // 3*128*256
    unsigned short* Mb    = cwb + 3*128*256;                // 128*128
    int*            ccnt  = (int*)(Mb + 128*128);           // NB*NCH
    int*            cbase = ccnt + NB*NCH;                  // NB*NCH
    int*            btot  = cbase + NB*NCH;                 // NB
    int*            bbase = btot + NB;                      // NB
    int*            offg  = bbase + NB;                     // N
    int*            degg  = offg + N;                       // N
    int*            csr   = degg + N;                       // E
    unsigned*       grouped = (unsigned*)(csr + E);         // E

    const int gblocks = (N + 127) / 128;
    const int nxb = (NX + 2047) / 2048;
    dim3 blk(256);

    // ---- prep0: p1hist || attn fold || weight cvt || x cvt ----
    prep0<<<NCH + 64 + 16 + 8 + 48 + nxb, blk, 0, stream>>>(
        x, xb, NX, fe_w1, w1b, fe_w2, w2b, conv_w, cwb,
        out_w, in_proj_w + (size_t)2*HID*HID, out_b, in_proj_b + 2*HID,
        Mb, bias2, ecol, ccnt, range, ch_sz, E);

    // ---- p2scan (coalesced, [NB][NCH] layout) ----
    p2scan<<<1, blk, 0, stream>>>(ccnt, cbase, btot, bbase);

    // ---- p3 scatter (first) || FE1 GEMM ----
    fe1_scat<<<NCH + gblocks, blk, 0, stream>>>(
        xb, w1b, fe_b1, hb1, N, erow, ecol, cbase, grouped, range, ch_sz, E);

    // ---- per-bucket node CSR (first) || FE2 GEMM ----
    fe2_csr2<<<nbk + gblocks, blk, 0, stream>>>(
        hb1, w2b, fe_b2, hb0, N, nbk, bbase, btot, grouped, range, N,
        offg, degg, csr);

    // ---- 3 x DynamicGraphConv ----
    unsigned short* h = hb0;
    unsigned short* other = hb1;
    const int wblocks = (int)(((size_t)N * 64 + 255) / 256);
    for (int l = 0; l < 3; l++) {
        gather_sum<<<wblocks, blk, 0, stream>>>(h, offg, degg, csr, nbrb, N);
        mgemm<256,true,true,true,false><<<gblocks, blk, 0, stream>>>(
            h, nbrb, cwb + (size_t)l*128*256, conv_b + l*HID,
            ln_g + l*HID, ln_b + l*HID, other, nullptr, N);
        unsigned short* t = h; h = other; other = t;
    }

    // ---- attention (folded) + pooling in epilogue ----
    mgemm<128,false,false,false,true><<<gblocks, blk, 0, stream>>>(
        h, nullptr, Mb, bias2, nullptr, nullptr, nullptr, part, N);

    // ---- pooling tail + classifier ----
    pool_reduce16<<<16, blk, 0, stream>>>(part, part2, gblocks);
    cls_fused<<<1, blk, 0, stream>>>(part2, N, c_w1, c_b1, c_w2, c_b2, out, CLASSES);
}